// Round 7
// baseline (235.175 us; speedup 1.0000x reference)
//
#include <hip/hip_runtime.h>

// Problem: B=32, S=256, M=1024, N=32, O=32.
// out[b][s*32+o] = sum_k exp(-sum_n |proj[b,s,n,o]-proj[b,k,n,o]|),
// proj[b,s,j] = sum_m x[b,s,m] W[j,m],  j = n*32+o.

#define BS 8192      // B*S rows of x
#define MD 1024      // M
#define NO 1024      // N*O

typedef short short8 __attribute__((ext_vector_type(8)));    // 8 bf16 raw bits
typedef float f32x4 __attribute__((ext_vector_type(4)));
typedef _Float16 f16x2 __attribute__((ext_vector_type(2)));

template <typename T, typename F>
__device__ __forceinline__ T bc(F f) { return __builtin_bit_cast(T, f); }

// ---------------- cast f32 -> bf16 (RNE), 4 elems/thread ----------------
__global__ __launch_bounds__(256) void cast_bf16_kernel(const float* __restrict__ in,
                                                        unsigned short* __restrict__ out,
                                                        int n4) {
  int i = blockIdx.x * 256 + threadIdx.x;
  if (i >= n4) return;
  float4 v = reinterpret_cast<const float4*>(in)[i];
  ushort4 u;
  unsigned b;
  b = __float_as_uint(v.x); u.x = (unsigned short)((b + 0x7FFFu + ((b >> 16) & 1u)) >> 16);
  b = __float_as_uint(v.y); u.y = (unsigned short)((b + 0x7FFFu + ((b >> 16) & 1u)) >> 16);
  b = __float_as_uint(v.z); u.z = (unsigned short)((b + 0x7FFFu + ((b >> 16) & 1u)) >> 16);
  b = __float_as_uint(v.w); u.w = (unsigned short)((b + 0x7FFFu + ((b >> 16) & 1u)) >> 16);
  reinterpret_cast<ushort4*>(out)[i] = u;
}

// ---------------- GEMM: proj[j][i] = sum_k W[j,k] x[i,k], emitted as
// projQ[o][i][m] = packed f16x2 (proj[n=2m], proj[n=2m+1]); 64 B per (o,i) row.
__global__ __launch_bounds__(256) void gemm_kernel(const unsigned short* __restrict__ xb,
                                                   const unsigned short* __restrict__ wb,
                                                   unsigned int* __restrict__ projQ) {
  const int lane = threadIdx.x & 63;
  const int w = threadIdx.x >> 6;
  const int wj = w >> 1, wi = w & 1;
  const int jt = blockIdx.y * 128 + wj * 64;   // multiple of 64
  const int it = blockIdx.x * 128 + wi * 64;
  const int c = lane & 15, h = lane >> 4;

  f32x4 acc[4][4];
#pragma unroll
  for (int m = 0; m < 4; m++)
#pragma unroll
    for (int n = 0; n < 4; n++) acc[m][n] = f32x4{0.f, 0.f, 0.f, 0.f};

  const unsigned short* wptr = wb + (size_t)(jt + c) * MD + h * 8;
  const unsigned short* xptr = xb + (size_t)(it + c) * MD + h * 8;

  for (int k0 = 0; k0 < MD; k0 += 32) {
    short8 a[4], bfr[4];
#pragma unroll
    for (int mm = 0; mm < 4; mm++)
      a[mm] = *reinterpret_cast<const short8*>(wptr + mm * 16 * MD + k0);
#pragma unroll
    for (int nn = 0; nn < 4; nn++)
      bfr[nn] = *reinterpret_cast<const short8*>(xptr + nn * 16 * MD + k0);
#pragma unroll
    for (int mm = 0; mm < 4; mm++)
#pragma unroll
      for (int nn = 0; nn < 4; nn++)
        acc[mm][nn] = __builtin_amdgcn_mfma_f32_16x16x32_bf16(a[mm], bfr[nn], acc[mm][nn], 0, 0, 0);
  }

  // epilogue: j = jt + 16*mm01 + 4*h + r (and j+32) -> m-word = jt>>6, o = j&31
  const int mglob = jt >> 6;
#pragma unroll
  for (int mm01 = 0; mm01 < 2; mm01++) {
#pragma unroll
    for (int r = 0; r < 4; r++) {
      const int o = mm01 * 16 + h * 4 + r;
      unsigned int* obp = projQ + (((size_t)o << 13) << 4);  // o*8192*16 words
#pragma unroll
      for (int nn = 0; nn < 4; nn++) {
        const size_t i = (size_t)(it + c + nn * 16);
        obp[i * 16 + mglob] = bc<unsigned int>(
            __builtin_amdgcn_cvt_pkrtz(acc[mm01][nn][r], acc[mm01 + 2][nn][r]));
      }
    }
  }
}

// ---------------- A[o][i] = f32 row-sum; 0-init ascending-m pk_add chain ----
// (must bit-match dist's S-chain so the diagonal stays exactly 0)
__global__ __launch_bounds__(256) void asum_kernel(const unsigned int* __restrict__ projQ,
                                                   float* __restrict__ A) {
  int idx = blockIdx.x * 256 + threadIdx.x;   // 32*8192 total
  int gi = idx & 8191, o = idx >> 13;
  const uint4* p = reinterpret_cast<const uint4*>(projQ + (((size_t)o << 13) + gi) * 16);
  uint4 q0 = p[0], q1 = p[1], q2 = p[2], q3 = p[3];
  f16x2 a = bc<f16x2>(0u);
  a = a + bc<f16x2>(q0.x); a = a + bc<f16x2>(q0.y); a = a + bc<f16x2>(q0.z); a = a + bc<f16x2>(q0.w);
  a = a + bc<f16x2>(q1.x); a = a + bc<f16x2>(q1.y); a = a + bc<f16x2>(q1.z); a = a + bc<f16x2>(q1.w);
  a = a + bc<f16x2>(q2.x); a = a + bc<f16x2>(q2.y); a = a + bc<f16x2>(q2.z); a = a + bc<f16x2>(q2.w);
  a = a + bc<f16x2>(q3.x); a = a + bc<f16x2>(q3.y); a = a + bc<f16x2>(q3.z); a = a + bc<f16x2>(q3.w);
  A[((size_t)o << 13) + gi] = (float)a[0] + (float)a[1];
}

// ---------------- phase 2: zero-LDS distance kernel ----------------
// Block = (b,o), 256 threads; lane owns ONE row (16 regs). k-row is a
// wave-uniform load (-> SGPRs / broadcast), 1-deep prefetch.
// Sum|a-b| = 2*Smax - A_i - A_k ; out += exp2(fmaf(S,-2,Ai+Ak)*log2e)
__global__ __launch_bounds__(256) void dist_kernel(const unsigned int* __restrict__ projQ,
                                                   const float* __restrict__ A,
                                                   float* __restrict__ out) {
  const int tid = threadIdx.x;
  const int o = blockIdx.x & 31, b = blockIdx.x >> 5;
  const size_t obase = ((size_t)o << 13) + b * 256;  // row-index base

  // my row (per-lane), 4x b128
  const uint4* rp = reinterpret_cast<const uint4*>(projQ + (obase + tid) * 16);
  const uint4 r0 = rp[0], r1 = rp[1], r2 = rp[2], r3 = rp[3];
  const float Ai = A[obase + tid];

  // prefetch k-row 0 (wave-uniform)
  const uint4* kp = reinterpret_cast<const uint4*>(projQ + obase * 16);
  uint4 c0 = kp[0], c1 = kp[1], c2 = kp[2], c3 = kp[3];
  float Ak = A[obase];

  float acc = 0.f;
#define STEP(rw, cw) s = s + __builtin_elementwise_max(bc<f16x2>(rw), bc<f16x2>(cw));
  for (int k = 0; k < 256; ++k) {
    const int kn = (k + 1) & 255;  // wrap: harmless re-prefetch of row 0
    const uint4* np = reinterpret_cast<const uint4*>(projQ + (obase + kn) * 16);
    const uint4 n0 = np[0], n1 = np[1], n2 = np[2], n3 = np[3];
    const float An = A[obase + kn];

    f16x2 s = bc<f16x2>(0u);
    STEP(r0.x, c0.x) STEP(r0.y, c0.y) STEP(r0.z, c0.z) STEP(r0.w, c0.w)
    STEP(r1.x, c1.x) STEP(r1.y, c1.y) STEP(r1.z, c1.z) STEP(r1.w, c1.w)
    STEP(r2.x, c2.x) STEP(r2.y, c2.y) STEP(r2.z, c2.z) STEP(r2.w, c2.w)
    STEP(r3.x, c3.x) STEP(r3.y, c3.y) STEP(r3.z, c3.z) STEP(r3.w, c3.w)
    const float Sf = (float)s[0] + (float)s[1];
    acc += exp2f(fmaf(Sf, -2.0f, Ai + Ak) * 1.4426950408889634f);

    c0 = n0; c1 = n1; c2 = n2; c3 = n3; Ak = An;
  }
#undef STEP

  out[(size_t)b * 8192 + (size_t)tid * 32 + o] = acc;
}

extern "C" void kernel_launch(void* const* d_in, const int* in_sizes, int n_in,
                              void* d_out, int out_size, void* d_ws, size_t ws_size,
                              hipStream_t stream) {
  const float* x = (const float*)d_in[0];   // (32,256,1024) f32
  const float* W = (const float*)d_in[1];   // (1024,1024) f32
  float* out = (float*)d_out;               // (32, 8192) f32

  char* ws = (char*)d_ws;
  unsigned short* xb = (unsigned short*)ws;                          // 16 MB
  unsigned short* wbf = (unsigned short*)(ws + (16u << 20));         //  2 MB
  unsigned int* projQ = (unsigned int*)(ws + (18u << 20));           // 16 MB
  float* Abuf = (float*)(ws + (34u << 20));                          //  1 MB

  {
    int n4 = (BS * MD) / 4;  // 2097152
    cast_bf16_kernel<<<(n4 + 255) / 256, 256, 0, stream>>>(x, xb, n4);
  }
  {
    int n4 = (NO * MD) / 4;  // 262144
    cast_bf16_kernel<<<(n4 + 255) / 256, 256, 0, stream>>>(W, wbf, n4);
  }
  {
    dim3 grid(BS / 128, NO / 128);  // (64, 8)
    gemm_kernel<<<grid, 256, 0, stream>>>(xb, wbf, projQ);
  }
  asum_kernel<<<(32 * BS) / 256, 256, 0, stream>>>(projQ, Abuf);
  dist_kernel<<<32 * 32, 256, 0, stream>>>(projQ, Abuf, out);
}

// Round 9
// 192.714 us; speedup vs baseline: 1.2203x; 1.2203x over previous
//
#include <hip/hip_runtime.h>

// Problem: B=32, S=256, M=1024, N=32, O=32.
// out[b][s*32+o] = sum_k exp(-sum_n |proj[b,s,n,o]-proj[b,k,n,o]|),
// proj[b,s,j] = sum_m x[b,s,m] W[j,m],  j = n*32+o.

#define BS 8192      // B*S rows of x
#define MD 1024      // M
#define NO 1024      // N*O

typedef short short8 __attribute__((ext_vector_type(8)));    // 8 bf16 raw bits
typedef float f32x4 __attribute__((ext_vector_type(4)));
typedef _Float16 f16x2 __attribute__((ext_vector_type(2)));
typedef unsigned u32x4 __attribute__((ext_vector_type(4)));

template <typename T, typename F>
__device__ __forceinline__ T bc(F f) { return __builtin_bit_cast(T, f); }

// v_pk_add_f16, both VGPR
__device__ __forceinline__ unsigned pk_add(unsigned a, unsigned b) {
  unsigned d;
  asm("v_pk_add_f16 %0, %1, %2" : "=v"(d) : "v"(a), "v"(b));
  return d;
}

// force a wave-uniform pointer into SGPRs (readfirstlane both halves)
template <typename T>
__device__ __forceinline__ const T* rfl(const T* p) {
  unsigned long long v = (unsigned long long)p;
  unsigned lo = __builtin_amdgcn_readfirstlane((unsigned)v);
  unsigned hi = __builtin_amdgcn_readfirstlane((unsigned)(v >> 32));
  return (const T*)(((unsigned long long)hi << 32) | (unsigned long long)lo);
}

// ---------------- cast f32 -> bf16 (RNE), 4 elems/thread ----------------
__global__ __launch_bounds__(256) void cast_bf16_kernel(const float* __restrict__ in,
                                                        unsigned short* __restrict__ out,
                                                        int n4) {
  int i = blockIdx.x * 256 + threadIdx.x;
  if (i >= n4) return;
  float4 v = reinterpret_cast<const float4*>(in)[i];
  ushort4 u;
  unsigned b;
  b = __float_as_uint(v.x); u.x = (unsigned short)((b + 0x7FFFu + ((b >> 16) & 1u)) >> 16);
  b = __float_as_uint(v.y); u.y = (unsigned short)((b + 0x7FFFu + ((b >> 16) & 1u)) >> 16);
  b = __float_as_uint(v.z); u.z = (unsigned short)((b + 0x7FFFu + ((b >> 16) & 1u)) >> 16);
  b = __float_as_uint(v.w); u.w = (unsigned short)((b + 0x7FFFu + ((b >> 16) & 1u)) >> 16);
  reinterpret_cast<ushort4*>(out)[i] = u;
}

// ---------------- GEMM: proj[j][i] = sum_k W[j,k] x[i,k], emitted as
// projQ[o][i][m] = packed f16x2 (proj[n=2m], proj[n=2m+1]); 64 B per (o,i) row.
__global__ __launch_bounds__(256) void gemm_kernel(const unsigned short* __restrict__ xb,
                                                   const unsigned short* __restrict__ wb,
                                                   unsigned int* __restrict__ projQ) {
  const int lane = threadIdx.x & 63;
  const int w = threadIdx.x >> 6;
  const int wj = w >> 1, wi = w & 1;
  const int jt = blockIdx.y * 128 + wj * 64;   // multiple of 64
  const int it = blockIdx.x * 128 + wi * 64;
  const int c = lane & 15, h = lane >> 4;

  f32x4 acc[4][4];
#pragma unroll
  for (int m = 0; m < 4; m++)
#pragma unroll
    for (int n = 0; n < 4; n++) acc[m][n] = f32x4{0.f, 0.f, 0.f, 0.f};

  const unsigned short* wptr = wb + (size_t)(jt + c) * MD + h * 8;
  const unsigned short* xptr = xb + (size_t)(it + c) * MD + h * 8;

  for (int k0 = 0; k0 < MD; k0 += 32) {
    short8 a[4], bfr[4];
#pragma unroll
    for (int mm = 0; mm < 4; mm++)
      a[mm] = *reinterpret_cast<const short8*>(wptr + mm * 16 * MD + k0);
#pragma unroll
    for (int nn = 0; nn < 4; nn++)
      bfr[nn] = *reinterpret_cast<const short8*>(xptr + nn * 16 * MD + k0);
#pragma unroll
    for (int mm = 0; mm < 4; mm++)
#pragma unroll
      for (int nn = 0; nn < 4; nn++)
        acc[mm][nn] = __builtin_amdgcn_mfma_f32_16x16x32_bf16(a[mm], bfr[nn], acc[mm][nn], 0, 0, 0);
  }

  // epilogue: j = jt + 16*mm01 + 4*h + r (and j+32) -> m-word = jt>>6, o = j&31
  const int mglob = jt >> 6;
#pragma unroll
  for (int mm01 = 0; mm01 < 2; mm01++) {
#pragma unroll
    for (int r = 0; r < 4; r++) {
      const int o = mm01 * 16 + h * 4 + r;
      unsigned int* obp = projQ + (((size_t)o << 13) << 4);  // o*8192*16 words
#pragma unroll
      for (int nn = 0; nn < 4; nn++) {
        const size_t i = (size_t)(it + c + nn * 16);
        obp[i * 16 + mglob] = bc<unsigned int>(
            __builtin_amdgcn_cvt_pkrtz(acc[mm01][nn][r], acc[mm01 + 2][nn][r]));
      }
    }
  }
}

// ---------------- A[o][i] = f32 row-sum; 0-init ascending-m pk_add chain ----
// (must bit-match dist's S-chain so the diagonal stays exactly 0)
__global__ __launch_bounds__(256) void asum_kernel(const unsigned int* __restrict__ projQ,
                                                   float* __restrict__ A) {
  int idx = blockIdx.x * 256 + threadIdx.x;   // 32*8192 total
  int gi = idx & 8191, o = idx >> 13;
  const uint4* p = reinterpret_cast<const uint4*>(projQ + (((size_t)o << 13) + gi) * 16);
  uint4 q0 = p[0], q1 = p[1], q2 = p[2], q3 = p[3];
  unsigned a = 0u;
  a = pk_add(a, q0.x); a = pk_add(a, q0.y); a = pk_add(a, q0.z); a = pk_add(a, q0.w);
  a = pk_add(a, q1.x); a = pk_add(a, q1.y); a = pk_add(a, q1.z); a = pk_add(a, q1.w);
  a = pk_add(a, q2.x); a = pk_add(a, q2.y); a = pk_add(a, q2.z); a = pk_add(a, q2.w);
  a = pk_add(a, q3.x); a = pk_add(a, q3.y); a = pk_add(a, q3.z); a = pk_add(a, q3.w);
  f16x2 af = bc<f16x2>(a);
  A[((size_t)o << 13) + gi] = (float)af[0] + (float)af[1];
}

// ---------------- phase 2: k-rows via SCALAR loads (SMEM), zero LDS/VMEM in loop ---
// Block = (b,o,ih): 256 thr; wave w owns k-quarter [64w,64w+64); lane t owns rows
// ih*128+t, ih*128+64+t (8 uint4 in VGPRs). k-row (64B) -> SGPRs via s_load_dwordx4,
// 1-deep prefetch. v_pk_max_f16 vgpr,sgpr. Sum|a-b| = 2*Smax - Ai - Ak.
__global__ __launch_bounds__(256) void dist_kernel(const unsigned int* __restrict__ projQ,
                                                   const float* __restrict__ A,
                                                   float* __restrict__ out) {
  const int tid = threadIdx.x;
  const int t = tid & 63;   // lane
  const int w = tid >> 6;   // wave = k-quarter
  const int bid = blockIdx.x;                   // 32b * 32o * 2ih
  const int ih = bid & 1, o = (bid >> 1) & 31, b = bid >> 6;
  const size_t obase = ((size_t)o << 13) + b * 256;  // global row-index base

  __shared__ float outp[4][128];     // 2 KB

  // my two rows, per-lane (VGPRs, named -> nothing to restructure)
  const uint4* PA = reinterpret_cast<const uint4*>(projQ + (obase + ih * 128 + t) * 16);
  const uint4 pa0 = PA[0], pa1 = PA[1], pa2 = PA[2], pa3 = PA[3];
  const uint4* PB = reinterpret_cast<const uint4*>(projQ + (obase + ih * 128 + 64 + t) * 16);
  const uint4 pb0 = PB[0], pb1 = PB[1], pb2 = PB[2], pb3 = PB[3];
  const float Ai0 = A[obase + ih * 128 + t];
  const float Ai1 = A[obase + ih * 128 + 64 + t];

  // this wave's k-quarter base — wave-uniform, forced into SGPRs
  const unsigned* kbase = rfl(projQ + (obase + w * 64) * 16);
  const float* abase = rfl(A + obase + w * 64);

  // prefetch k-row 0 into SGPRs
  u32x4 c0, c1, c2, c3; unsigned cA;
  asm("s_load_dwordx4 %0, %1, 0x0"  : "=s"(c0) : "s"(kbase));
  asm("s_load_dwordx4 %0, %1, 0x10" : "=s"(c1) : "s"(kbase));
  asm("s_load_dwordx4 %0, %1, 0x20" : "=s"(c2) : "s"(kbase));
  asm("s_load_dwordx4 %0, %1, 0x30" : "=s"(c3) : "s"(kbase));
  asm("s_load_dword %0, %1, 0x0" : "=s"(cA) : "s"(abase));
  asm("s_waitcnt lgkmcnt(0)" : "+s"(c0), "+s"(c1), "+s"(c2), "+s"(c3), "+s"(cA));

  // s = pk_add(s, pk_max(row_word, k_word)), m ascending, 0-init (matches asum)
#define PK2(acc_, pw_, kw_) do {                                        \
    unsigned t0_;                                                       \
    asm("v_pk_max_f16 %0, %1, %2" : "=v"(t0_) : "v"(pw_), "s"(kw_));    \
    asm("v_pk_add_f16 %0, %1, %2" : "=v"(acc_) : "v"(acc_), "v"(t0_));  \
  } while (0)

  float outv0 = 0.f, outv1 = 0.f;
#pragma unroll 2
  for (int k = 0; k < 64; ++k) {
    // issue next-row prefetch (wrap at 63: harmless re-read of row 0)
    const int kn = (k + 1) & 63;
    const unsigned* kr = kbase + kn * 16;
    u32x4 n0, n1, n2, n3; unsigned nA;
    asm("s_load_dwordx4 %0, %1, 0x0"  : "=s"(n0) : "s"(kr));
    asm("s_load_dwordx4 %0, %1, 0x10" : "=s"(n1) : "s"(kr));
    asm("s_load_dwordx4 %0, %1, 0x20" : "=s"(n2) : "s"(kr));
    asm("s_load_dwordx4 %0, %1, 0x30" : "=s"(n3) : "s"(kr));
    asm("s_load_dword %0, %1, 0x0" : "=s"(nA) : "s"(abase + kn));

    unsigned s0 = 0u, s1 = 0u;
    PK2(s0, pa0.x, c0.x); PK2(s0, pa0.y, c0.y); PK2(s0, pa0.z, c0.z); PK2(s0, pa0.w, c0.w);
    PK2(s0, pa1.x, c1.x); PK2(s0, pa1.y, c1.y); PK2(s0, pa1.z, c1.z); PK2(s0, pa1.w, c1.w);
    PK2(s0, pa2.x, c2.x); PK2(s0, pa2.y, c2.y); PK2(s0, pa2.z, c2.z); PK2(s0, pa2.w, c2.w);
    PK2(s0, pa3.x, c3.x); PK2(s0, pa3.y, c3.y); PK2(s0, pa3.z, c3.z); PK2(s0, pa3.w, c3.w);
    PK2(s1, pb0.x, c0.x); PK2(s1, pb0.y, c0.y); PK2(s1, pb0.z, c0.z); PK2(s1, pb0.w, c0.w);
    PK2(s1, pb1.x, c1.x); PK2(s1, pb1.y, c1.y); PK2(s1, pb1.z, c1.z); PK2(s1, pb1.w, c1.w);
    PK2(s1, pb2.x, c2.x); PK2(s1, pb2.y, c2.y); PK2(s1, pb2.z, c2.z); PK2(s1, pb2.w, c2.w);
    PK2(s1, pb3.x, c3.x); PK2(s1, pb3.y, c3.y); PK2(s1, pb3.z, c3.z); PK2(s1, pb3.w, c3.w);

    const float Akf = __builtin_bit_cast(float, cA);
    const f16x2 h0 = bc<f16x2>(s0), h1 = bc<f16x2>(s1);
    const float S0 = (float)h0[0] + (float)h0[1];
    const float S1 = (float)h1[0] + (float)h1[1];
    outv0 += exp2f(fmaf(S0, -2.0f, Ai0 + Akf) * 1.4426950408889634f);
    outv1 += exp2f(fmaf(S1, -2.0f, Ai1 + Akf) * 1.4426950408889634f);

    // retire prefetch, rotate
    asm("s_waitcnt lgkmcnt(0)" : "+s"(n0), "+s"(n1), "+s"(n2), "+s"(n3), "+s"(nA));
    c0 = n0; c1 = n1; c2 = n2; c3 = n3; cA = nA;
  }
#undef PK2

  // cross-wave reduction over the 4 k-quarters, then direct store
  outp[w][t] = outv0;
  outp[w][64 + t] = outv1;
  __syncthreads();
  if (tid < 128) {
    float v = outp[0][tid] + outp[1][tid] + outp[2][tid] + outp[3][tid];
    out[(size_t)b * 8192 + (size_t)(ih * 128 + tid) * 32 + o] = v;
  }
}

extern "C" void kernel_launch(void* const* d_in, const int* in_sizes, int n_in,
                              void* d_out, int out_size, void* d_ws, size_t ws_size,
                              hipStream_t stream) {
  const float* x = (const float*)d_in[0];   // (32,256,1024) f32
  const float* W = (const float*)d_in[1];   // (1024,1024) f32
  float* out = (float*)d_out;               // (32, 8192) f32

  char* ws = (char*)d_ws;
  unsigned short* xb = (unsigned short*)ws;                          // 16 MB
  unsigned short* wbf = (unsigned short*)(ws + (16u << 20));         //  2 MB
  unsigned int* projQ = (unsigned int*)(ws + (18u << 20));           // 16 MB
  float* Abuf = (float*)(ws + (34u << 20));                          //  1 MB

  {
    int n4 = (BS * MD) / 4;  // 2097152
    cast_bf16_kernel<<<(n4 + 255) / 256, 256, 0, stream>>>(x, xb, n4);
  }
  {
    int n4 = (NO * MD) / 4;  // 262144
    cast_bf16_kernel<<<(n4 + 255) / 256, 256, 0, stream>>>(W, wbf, n4);
  }
  {
    dim3 grid(BS / 128, NO / 128);  // (64, 8)
    gemm_kernel<<<grid, 256, 0, stream>>>(xb, wbf, projQ);
  }
  asum_kernel<<<(32 * BS) / 256, 256, 0, stream>>>(projQ, Abuf);
  dist_kernel<<<32 * 32 * 2, 256, 0, stream>>>(projQ, Abuf, out);
}

// Round 10
// 152.085 us; speedup vs baseline: 1.5463x; 1.2671x over previous
//
#include <hip/hip_runtime.h>

// Problem: B=32, S=256, M=1024, N=32, O=32.
// out[b][s*32+o] = sum_k exp(-sum_n |proj[b,s,n,o]-proj[b,k,n,o]|),
// proj[b,s,j] = sum_m x[b,s,m] W[j,m],  j = n*32+o.

#define BS 8192      // B*S rows of x
#define MD 1024      // M
#define NO 1024      // N*O

typedef short short8 __attribute__((ext_vector_type(8)));    // 8 bf16 raw bits
typedef float f32x4 __attribute__((ext_vector_type(4)));
typedef _Float16 f16x2 __attribute__((ext_vector_type(2)));
typedef unsigned u32x4 __attribute__((ext_vector_type(4)));

template <typename T, typename F>
__device__ __forceinline__ T bc(F f) { return __builtin_bit_cast(T, f); }

// v_pk_add_f16, both VGPR
__device__ __forceinline__ unsigned pk_add(unsigned a, unsigned b) {
  unsigned d;
  asm("v_pk_add_f16 %0, %1, %2" : "=v"(d) : "v"(a), "v"(b));
  return d;
}

// force a wave-uniform pointer into SGPRs (readfirstlane both halves)
template <typename T>
__device__ __forceinline__ const T* rfl(const T* p) {
  unsigned long long v = (unsigned long long)p;
  unsigned lo = __builtin_amdgcn_readfirstlane((unsigned)v);
  unsigned hi = __builtin_amdgcn_readfirstlane((unsigned)(v >> 32));
  return (const T*)(((unsigned long long)hi << 32) | (unsigned long long)lo);
}

// ---------------- fused cast f32 -> bf16 (RNE) for x and W ----------------
#define N4X ((BS * MD) / 4)   // 2097152 float4 groups in x
#define N4W ((NO * MD) / 4)   //  262144 in W
__global__ __launch_bounds__(256) void cast_bf16_kernel(const float* __restrict__ x,
                                                        const float* __restrict__ W,
                                                        unsigned short* __restrict__ xb,
                                                        unsigned short* __restrict__ wb) {
  int i = blockIdx.x * 256 + threadIdx.x;
  const float* in;
  unsigned short* out;
  if (i < N4X) { in = x; out = xb; }
  else { i -= N4X; if (i >= N4W) return; in = W; out = wb; }
  float4 v = reinterpret_cast<const float4*>(in)[i];
  ushort4 u;
  unsigned b;
  b = __float_as_uint(v.x); u.x = (unsigned short)((b + 0x7FFFu + ((b >> 16) & 1u)) >> 16);
  b = __float_as_uint(v.y); u.y = (unsigned short)((b + 0x7FFFu + ((b >> 16) & 1u)) >> 16);
  b = __float_as_uint(v.z); u.z = (unsigned short)((b + 0x7FFFu + ((b >> 16) & 1u)) >> 16);
  b = __float_as_uint(v.w); u.w = (unsigned short)((b + 0x7FFFu + ((b >> 16) & 1u)) >> 16);
  reinterpret_cast<ushort4*>(out)[i] = u;
}

// ---------------- GEMM (m97-style): C[j,i] = sum_k W[j,k] x[i,k] ----------------
// 128(j) x 128(i) tile, BK=64, global_load_lds(16B) staging, XOR-swizzled LDS
// (swizzle applied on the GLOBAL source so LDS dest stays linear; reads use the
// same XOR). Emits projQ[o][i][m] packed f16x2 (n=2m, n=2m+1).
__global__ __launch_bounds__(256) void gemm_kernel(const unsigned short* __restrict__ xb,
                                                   const unsigned short* __restrict__ wb,
                                                   unsigned int* __restrict__ projQ) {
  const int tid = threadIdx.x;
  const int lane = tid & 63;
  const int w = tid >> 6;
  const int wj = w >> 1, wi = w & 1;           // wave quadrant (64x64)
  const int jt = blockIdx.y * 128;
  const int it = blockIdx.x * 128;
  const int c = lane & 15, h = lane >> 4;

  __shared__ unsigned short Wl[128 * 64];      // 16 KB, row-major [row][64k], swizzled
  __shared__ unsigned short Xl[128 * 64];      // 16 KB

  f32x4 acc[4][4] = {};

  for (int k0 = 0; k0 < MD; k0 += 64) {
    // ---- stage: 1024 16B-segs per matrix; seg p -> row=p>>3, phys kseg=p&7,
    // holds global kseg (p&7)^(row&7). LDS dest linear: base + lane*16.
#pragma unroll
    for (int rep = 0; rep < 4; rep++) {
      const int p = rep * 256 + w * 64 + lane;
      const int row = p >> 3;
      const int ksg = (p & 7) ^ (row & 7);
      const unsigned short* gw = wb + (size_t)(jt + row) * MD + k0 + ksg * 8;
      const unsigned short* gx = xb + (size_t)(it + row) * MD + k0 + ksg * 8;
      __builtin_amdgcn_global_load_lds(
          (const __attribute__((address_space(1))) void*)gw,
          (__attribute__((address_space(3))) void*)((char*)Wl + rep * 4096 + w * 1024),
          16, 0, 0);
      __builtin_amdgcn_global_load_lds(
          (const __attribute__((address_space(1))) void*)gx,
          (__attribute__((address_space(3))) void*)((char*)Xl + rep * 4096 + w * 1024),
          16, 0, 0);
    }
    __syncthreads();  // drains vmcnt(0): staged data visible

    // ---- compute: 2 k-subs x 16 MFMA. frag (row r, kseg ks) at byte
    // r*128 + ((ks ^ (r&7)) * 16); A rows = j, B rows = i.
#pragma unroll
    for (int ks = 0; ks < 2; ks++) {
      short8 af[4], bf[4];
#pragma unroll
      for (int mm = 0; mm < 4; mm++) {
        const int rl = wj * 64 + mm * 16 + c;
        af[mm] = *reinterpret_cast<const short8*>(
            (const char*)Wl + rl * 128 + (((ks * 4 + h) ^ (rl & 7)) * 16));
      }
#pragma unroll
      for (int nn = 0; nn < 4; nn++) {
        const int rl = wi * 64 + nn * 16 + c;
        bf[nn] = *reinterpret_cast<const short8*>(
            (const char*)Xl + rl * 128 + (((ks * 4 + h) ^ (rl & 7)) * 16));
      }
#pragma unroll
      for (int mm = 0; mm < 4; mm++)
#pragma unroll
        for (int nn = 0; nn < 4; nn++)
          acc[mm][nn] = __builtin_amdgcn_mfma_f32_16x16x32_bf16(af[mm], bf[nn], acc[mm][nn], 0, 0, 0);
    }
    __syncthreads();  // all waves done reading before next stage overwrites
  }

  // ---- epilogue: j = jt + wj*64 + mm01*16 + (h*4+r) [+32 for mm01+2]
  // o = mm01*16 + h*4 + r, m-word = (jt + wj*64)>>6, i = it + wi*64 + nn*16 + c
  const int mbase = (jt + wj * 64) >> 6;
#pragma unroll
  for (int mm01 = 0; mm01 < 2; mm01++) {
#pragma unroll
    for (int r = 0; r < 4; r++) {
      const int o = mm01 * 16 + h * 4 + r;
#pragma unroll
      for (int nn = 0; nn < 4; nn++) {
        const size_t i = (size_t)(it + wi * 64 + nn * 16 + c);
        projQ[(((size_t)o << 13) + i) * 16 + mbase] = bc<unsigned int>(
            __builtin_amdgcn_cvt_pkrtz(acc[mm01][nn][r], acc[mm01 + 2][nn][r]));
      }
    }
  }
}

// ---------------- A[o][i] = f32 row-sum; 0-init ascending-m pk_add chain ----
// (must bit-match dist's S-chain so the diagonal stays exactly 0)
__global__ __launch_bounds__(256) void asum_kernel(const unsigned int* __restrict__ projQ,
                                                   float* __restrict__ A) {
  int idx = blockIdx.x * 256 + threadIdx.x;   // 32*8192 total
  int gi = idx & 8191, o = idx >> 13;
  const uint4* p = reinterpret_cast<const uint4*>(projQ + (((size_t)o << 13) + gi) * 16);
  uint4 q0 = p[0], q1 = p[1], q2 = p[2], q3 = p[3];
  unsigned a = 0u;
  a = pk_add(a, q0.x); a = pk_add(a, q0.y); a = pk_add(a, q0.z); a = pk_add(a, q0.w);
  a = pk_add(a, q1.x); a = pk_add(a, q1.y); a = pk_add(a, q1.z); a = pk_add(a, q1.w);
  a = pk_add(a, q2.x); a = pk_add(a, q2.y); a = pk_add(a, q2.z); a = pk_add(a, q2.w);
  a = pk_add(a, q3.x); a = pk_add(a, q3.y); a = pk_add(a, q3.z); a = pk_add(a, q3.w);
  f16x2 af = bc<f16x2>(a);
  A[((size_t)o << 13) + gi] = (float)af[0] + (float)af[1];
}

// ---------------- phase 2: k-rows via SCALAR loads (SMEM), zero LDS/VMEM in loop ---
__global__ __launch_bounds__(256) void dist_kernel(const unsigned int* __restrict__ projQ,
                                                   const float* __restrict__ A,
                                                   float* __restrict__ out) {
  const int tid = threadIdx.x;
  const int t = tid & 63;   // lane
  const int w = tid >> 6;   // wave = k-quarter
  const int bid = blockIdx.x;                   // 32b * 32o * 2ih
  const int ih = bid & 1, o = (bid >> 1) & 31, b = bid >> 6;
  const size_t obase = ((size_t)o << 13) + b * 256;  // global row-index base

  __shared__ float outp[4][128];     // 2 KB

  // my two rows, per-lane (VGPRs, named -> nothing to restructure)
  const uint4* PA = reinterpret_cast<const uint4*>(projQ + (obase + ih * 128 + t) * 16);
  const uint4 pa0 = PA[0], pa1 = PA[1], pa2 = PA[2], pa3 = PA[3];
  const uint4* PB = reinterpret_cast<const uint4*>(projQ + (obase + ih * 128 + 64 + t) * 16);
  const uint4 pb0 = PB[0], pb1 = PB[1], pb2 = PB[2], pb3 = PB[3];
  const float Ai0 = A[obase + ih * 128 + t];
  const float Ai1 = A[obase + ih * 128 + 64 + t];

  // this wave's k-quarter base — wave-uniform, forced into SGPRs
  const unsigned* kbase = rfl(projQ + (obase + w * 64) * 16);
  const float* abase = rfl(A + obase + w * 64);

  // prefetch k-row 0 into SGPRs
  u32x4 c0, c1, c2, c3; unsigned cA;
  asm("s_load_dwordx4 %0, %1, 0x0"  : "=s"(c0) : "s"(kbase));
  asm("s_load_dwordx4 %0, %1, 0x10" : "=s"(c1) : "s"(kbase));
  asm("s_load_dwordx4 %0, %1, 0x20" : "=s"(c2) : "s"(kbase));
  asm("s_load_dwordx4 %0, %1, 0x30" : "=s"(c3) : "s"(kbase));
  asm("s_load_dword %0, %1, 0x0" : "=s"(cA) : "s"(abase));
  asm("s_waitcnt lgkmcnt(0)" : "+s"(c0), "+s"(c1), "+s"(c2), "+s"(c3), "+s"(cA));

  // s = pk_add(s, pk_max(row_word, k_word)), m ascending, 0-init (matches asum)
#define PK2(acc_, pw_, kw_) do {                                        \
    unsigned t0_;                                                       \
    asm("v_pk_max_f16 %0, %1, %2" : "=v"(t0_) : "v"(pw_), "s"(kw_));    \
    asm("v_pk_add_f16 %0, %1, %2" : "=v"(acc_) : "v"(acc_), "v"(t0_));  \
  } while (0)

  float outv0 = 0.f, outv1 = 0.f;
#pragma unroll 2
  for (int k = 0; k < 64; ++k) {
    // issue next-row prefetch (wrap at 63: harmless re-read of row 0)
    const int kn = (k + 1) & 63;
    const unsigned* kr = kbase + kn * 16;
    u32x4 n0, n1, n2, n3; unsigned nA;
    asm("s_load_dwordx4 %0, %1, 0x0"  : "=s"(n0) : "s"(kr));
    asm("s_load_dwordx4 %0, %1, 0x10" : "=s"(n1) : "s"(kr));
    asm("s_load_dwordx4 %0, %1, 0x20" : "=s"(n2) : "s"(kr));
    asm("s_load_dwordx4 %0, %1, 0x30" : "=s"(n3) : "s"(kr));
    asm("s_load_dword %0, %1, 0x0" : "=s"(nA) : "s"(abase + kn));

    unsigned s0 = 0u, s1 = 0u;
    PK2(s0, pa0.x, c0.x); PK2(s0, pa0.y, c0.y); PK2(s0, pa0.z, c0.z); PK2(s0, pa0.w, c0.w);
    PK2(s0, pa1.x, c1.x); PK2(s0, pa1.y, c1.y); PK2(s0, pa1.z, c1.z); PK2(s0, pa1.w, c1.w);
    PK2(s0, pa2.x, c2.x); PK2(s0, pa2.y, c2.y); PK2(s0, pa2.z, c2.z); PK2(s0, pa2.w, c2.w);
    PK2(s0, pa3.x, c3.x); PK2(s0, pa3.y, c3.y); PK2(s0, pa3.z, c3.z); PK2(s0, pa3.w, c3.w);
    PK2(s1, pb0.x, c0.x); PK2(s1, pb0.y, c0.y); PK2(s1, pb0.z, c0.z); PK2(s1, pb0.w, c0.w);
    PK2(s1, pb1.x, c1.x); PK2(s1, pb1.y, c1.y); PK2(s1, pb1.z, c1.z); PK2(s1, pb1.w, c1.w);
    PK2(s1, pb2.x, c2.x); PK2(s1, pb2.y, c2.y); PK2(s1, pb2.z, c2.z); PK2(s1, pb2.w, c2.w);
    PK2(s1, pb3.x, c3.x); PK2(s1, pb3.y, c3.y); PK2(s1, pb3.z, c3.z); PK2(s1, pb3.w, c3.w);

    const float Akf = __builtin_bit_cast(float, cA);
    const f16x2 h0 = bc<f16x2>(s0), h1 = bc<f16x2>(s1);
    const float S0 = (float)h0[0] + (float)h0[1];
    const float S1 = (float)h1[0] + (float)h1[1];
    outv0 += exp2f(fmaf(S0, -2.0f, Ai0 + Akf) * 1.4426950408889634f);
    outv1 += exp2f(fmaf(S1, -2.0f, Ai1 + Akf) * 1.4426950408889634f);

    // retire prefetch, rotate
    asm("s_waitcnt lgkmcnt(0)" : "+s"(n0), "+s"(n1), "+s"(n2), "+s"(n3), "+s"(nA));
    c0 = n0; c1 = n1; c2 = n2; c3 = n3; cA = nA;
  }
#undef PK2

  // cross-wave reduction over the 4 k-quarters, then direct store
  outp[w][t] = outv0;
  outp[w][64 + t] = outv1;
  __syncthreads();
  if (tid < 128) {
    float v = outp[0][tid] + outp[1][tid] + outp[2][tid] + outp[3][tid];
    out[(size_t)b * 8192 + (size_t)(ih * 128 + tid) * 32 + o] = v;
  }
}

extern "C" void kernel_launch(void* const* d_in, const int* in_sizes, int n_in,
                              void* d_out, int out_size, void* d_ws, size_t ws_size,
                              hipStream_t stream) {
  const float* x = (const float*)d_in[0];   // (32,256,1024) f32
  const float* W = (const float*)d_in[1];   // (1024,1024) f32
  float* out = (float*)d_out;               // (32, 8192) f32

  char* ws = (char*)d_ws;
  unsigned short* xb = (unsigned short*)ws;                          // 16 MB
  unsigned short* wbf = (unsigned short*)(ws + (16u << 20));         //  2 MB
  unsigned int* projQ = (unsigned int*)(ws + (18u << 20));           // 16 MB
  float* Abuf = (float*)(ws + (34u << 20));                          //  1 MB

  {
    int n4 = N4X + N4W;  // 2359296
    cast_bf16_kernel<<<(n4 + 255) / 256, 256, 0, stream>>>(x, W, xb, wbf);
  }
  {
    dim3 grid(BS / 128, NO / 128);  // (64, 8)
    gemm_kernel<<<grid, 256, 0, stream>>>(xb, wbf, projQ);
  }
  asum_kernel<<<(32 * BS) / 256, 256, 0, stream>>>(projQ, Abuf);
  dist_kernel<<<32 * 32 * 2, 256, 0, stream>>>(projQ, Abuf, out);
}

// Round 11
// 144.884 us; speedup vs baseline: 1.6232x; 1.0497x over previous
//
#include <hip/hip_runtime.h>

// Problem: B=32, S=256, M=1024, N=32, O=32.
// out[b][s*32+o] = sum_k exp(-sum_n |proj[b,s,n,o]-proj[b,k,n,o]|),
// proj[b,s,j] = sum_m x[b,s,m] W[j,m],  j = n*32+o.

#define BS 8192      // B*S rows of x
#define MD 1024      // M
#define NO 1024      // N*O

typedef short short8 __attribute__((ext_vector_type(8)));    // 8 bf16 raw bits
typedef float f32x4 __attribute__((ext_vector_type(4)));
typedef _Float16 f16x2 __attribute__((ext_vector_type(2)));
typedef unsigned u32x4 __attribute__((ext_vector_type(4)));

template <typename T, typename F>
__device__ __forceinline__ T bc(F f) { return __builtin_bit_cast(T, f); }

// v_pk_add_f16, both VGPR
__device__ __forceinline__ unsigned pk_add(unsigned a, unsigned b) {
  unsigned d;
  asm("v_pk_add_f16 %0, %1, %2" : "=v"(d) : "v"(a), "v"(b));
  return d;
}

// force a wave-uniform pointer into SGPRs (readfirstlane both halves)
template <typename T>
__device__ __forceinline__ const T* rfl(const T* p) {
  unsigned long long v = (unsigned long long)p;
  unsigned lo = __builtin_amdgcn_readfirstlane((unsigned)v);
  unsigned hi = __builtin_amdgcn_readfirstlane((unsigned)(v >> 32));
  return (const T*)(((unsigned long long)hi << 32) | (unsigned long long)lo);
}

// ---------------- fused cast f32 -> bf16 (RNE) for x and W ----------------
#define N4X ((BS * MD) / 4)   // 2097152 float4 groups in x
#define N4W ((NO * MD) / 4)   //  262144 in W
__global__ __launch_bounds__(256) void cast_bf16_kernel(const float* __restrict__ x,
                                                        const float* __restrict__ W,
                                                        unsigned short* __restrict__ xb,
                                                        unsigned short* __restrict__ wb) {
  int i = blockIdx.x * 256 + threadIdx.x;
  const float* in;
  unsigned short* out;
  if (i < N4X) { in = x; out = xb; }
  else { i -= N4X; if (i >= N4W) return; in = W; out = wb; }
  float4 v = reinterpret_cast<const float4*>(in)[i];
  ushort4 u;
  unsigned b;
  b = __float_as_uint(v.x); u.x = (unsigned short)((b + 0x7FFFu + ((b >> 16) & 1u)) >> 16);
  b = __float_as_uint(v.y); u.y = (unsigned short)((b + 0x7FFFu + ((b >> 16) & 1u)) >> 16);
  b = __float_as_uint(v.z); u.z = (unsigned short)((b + 0x7FFFu + ((b >> 16) & 1u)) >> 16);
  b = __float_as_uint(v.w); u.w = (unsigned short)((b + 0x7FFFu + ((b >> 16) & 1u)) >> 16);
  reinterpret_cast<ushort4*>(out)[i] = u;
}

// ---------------- GEMM (m97-style): C[j,i] = sum_k W[j,k] x[i,k] ----------------
__global__ __launch_bounds__(256) void gemm_kernel(const unsigned short* __restrict__ xb,
                                                   const unsigned short* __restrict__ wb,
                                                   unsigned int* __restrict__ projQ) {
  const int tid = threadIdx.x;
  const int lane = tid & 63;
  const int w = tid >> 6;
  const int wj = w >> 1, wi = w & 1;           // wave quadrant (64x64)
  const int jt = blockIdx.y * 128;
  const int it = blockIdx.x * 128;
  const int c = lane & 15, h = lane >> 4;

  __shared__ unsigned short Wl[128 * 64];      // 16 KB, row-major [row][64k], swizzled
  __shared__ unsigned short Xl[128 * 64];      // 16 KB

  f32x4 acc[4][4] = {};

  for (int k0 = 0; k0 < MD; k0 += 64) {
#pragma unroll
    for (int rep = 0; rep < 4; rep++) {
      const int p = rep * 256 + w * 64 + lane;
      const int row = p >> 3;
      const int ksg = (p & 7) ^ (row & 7);
      const unsigned short* gw = wb + (size_t)(jt + row) * MD + k0 + ksg * 8;
      const unsigned short* gx = xb + (size_t)(it + row) * MD + k0 + ksg * 8;
      __builtin_amdgcn_global_load_lds(
          (const __attribute__((address_space(1))) void*)gw,
          (__attribute__((address_space(3))) void*)((char*)Wl + rep * 4096 + w * 1024),
          16, 0, 0);
      __builtin_amdgcn_global_load_lds(
          (const __attribute__((address_space(1))) void*)gx,
          (__attribute__((address_space(3))) void*)((char*)Xl + rep * 4096 + w * 1024),
          16, 0, 0);
    }
    __syncthreads();

#pragma unroll
    for (int ks = 0; ks < 2; ks++) {
      short8 af[4], bf[4];
#pragma unroll
      for (int mm = 0; mm < 4; mm++) {
        const int rl = wj * 64 + mm * 16 + c;
        af[mm] = *reinterpret_cast<const short8*>(
            (const char*)Wl + rl * 128 + (((ks * 4 + h) ^ (rl & 7)) * 16));
      }
#pragma unroll
      for (int nn = 0; nn < 4; nn++) {
        const int rl = wi * 64 + nn * 16 + c;
        bf[nn] = *reinterpret_cast<const short8*>(
            (const char*)Xl + rl * 128 + (((ks * 4 + h) ^ (rl & 7)) * 16));
      }
#pragma unroll
      for (int mm = 0; mm < 4; mm++)
#pragma unroll
        for (int nn = 0; nn < 4; nn++)
          acc[mm][nn] = __builtin_amdgcn_mfma_f32_16x16x32_bf16(af[mm], bf[nn], acc[mm][nn], 0, 0, 0);
    }
    __syncthreads();
  }

  const int mbase = (jt + wj * 64) >> 6;
#pragma unroll
  for (int mm01 = 0; mm01 < 2; mm01++) {
#pragma unroll
    for (int r = 0; r < 4; r++) {
      const int o = mm01 * 16 + h * 4 + r;
#pragma unroll
      for (int nn = 0; nn < 4; nn++) {
        const size_t i = (size_t)(it + wi * 64 + nn * 16 + c);
        projQ[(((size_t)o << 13) + i) * 16 + mbase] = bc<unsigned int>(
            __builtin_amdgcn_cvt_pkrtz(acc[mm01][nn][r], acc[mm01 + 2][nn][r]));
      }
    }
  }
}

// ---------------- A[o][i] = f32 row-sum; 0-init ascending-m pk_add chain ----
__global__ __launch_bounds__(256) void asum_kernel(const unsigned int* __restrict__ projQ,
                                                   float* __restrict__ A) {
  int idx = blockIdx.x * 256 + threadIdx.x;   // 32*8192 total
  int gi = idx & 8191, o = idx >> 13;
  const uint4* p = reinterpret_cast<const uint4*>(projQ + (((size_t)o << 13) + gi) * 16);
  uint4 q0 = p[0], q1 = p[1], q2 = p[2], q3 = p[3];
  unsigned a = 0u;
  a = pk_add(a, q0.x); a = pk_add(a, q0.y); a = pk_add(a, q0.z); a = pk_add(a, q0.w);
  a = pk_add(a, q1.x); a = pk_add(a, q1.y); a = pk_add(a, q1.z); a = pk_add(a, q1.w);
  a = pk_add(a, q2.x); a = pk_add(a, q2.y); a = pk_add(a, q2.z); a = pk_add(a, q2.w);
  a = pk_add(a, q3.x); a = pk_add(a, q3.y); a = pk_add(a, q3.z); a = pk_add(a, q3.w);
  f16x2 af = bc<f16x2>(a);
  A[((size_t)o << 13) + gi] = (float)af[0] + (float)af[1];
}

// ---------------- phase 2: 4 rows/lane, k-rows via SMEM scalar broadcast ----------
// Block = (b,o): 4 waves; wave w owns k-quarter [64w,64w+64); lane t owns rows
// {t, t+64, t+128, t+192} (16 uint4 in VGPRs). Per iter: ~156 VALU >> SMEM latency.
__global__ __launch_bounds__(256) void dist_kernel(const unsigned int* __restrict__ projQ,
                                                   const float* __restrict__ A,
                                                   float* __restrict__ out) {
  const int tid = threadIdx.x;
  const int t = tid & 63;   // lane
  const int w = tid >> 6;   // wave = k-quarter
  const int bid = blockIdx.x;                   // 32b * 32o
  const int o = bid & 31, b = bid >> 5;
  const size_t obase = ((size_t)o << 13) + b * 256;  // global row-index base

  __shared__ float outp[4][256];     // 4 KB

  // my four rows, per-lane (named uint4s -> nothing to restructure)
  const uint4* PA = reinterpret_cast<const uint4*>(projQ + (obase + t) * 16);
  const uint4 pa0 = PA[0], pa1 = PA[1], pa2 = PA[2], pa3 = PA[3];
  const uint4* PB = reinterpret_cast<const uint4*>(projQ + (obase + 64 + t) * 16);
  const uint4 pb0 = PB[0], pb1 = PB[1], pb2 = PB[2], pb3 = PB[3];
  const uint4* PC = reinterpret_cast<const uint4*>(projQ + (obase + 128 + t) * 16);
  const uint4 pc0 = PC[0], pc1 = PC[1], pc2 = PC[2], pc3 = PC[3];
  const uint4* PD = reinterpret_cast<const uint4*>(projQ + (obase + 192 + t) * 16);
  const uint4 pd0 = PD[0], pd1 = PD[1], pd2 = PD[2], pd3 = PD[3];
  const float Ai0 = A[obase + t];
  const float Ai1 = A[obase + 64 + t];
  const float Ai2 = A[obase + 128 + t];
  const float Ai3 = A[obase + 192 + t];

  // this wave's k-quarter base — wave-uniform, forced into SGPRs
  const unsigned* kbase = rfl(projQ + (obase + w * 64) * 16);
  const float* abase = rfl(A + obase + w * 64);

  // prefetch k-row 0 into SGPRs
  u32x4 c0, c1, c2, c3; unsigned cA;
  asm("s_load_dwordx4 %0, %1, 0x0"  : "=s"(c0) : "s"(kbase));
  asm("s_load_dwordx4 %0, %1, 0x10" : "=s"(c1) : "s"(kbase));
  asm("s_load_dwordx4 %0, %1, 0x20" : "=s"(c2) : "s"(kbase));
  asm("s_load_dwordx4 %0, %1, 0x30" : "=s"(c3) : "s"(kbase));
  asm("s_load_dword %0, %1, 0x0" : "=s"(cA) : "s"(abase));
  asm("s_waitcnt lgkmcnt(0)" : "+s"(c0), "+s"(c1), "+s"(c2), "+s"(c3), "+s"(cA));

  // s = pk_add(s, pk_max(row_word, k_word)), m ascending, 0-init (matches asum)
#define PK2(acc_, pw_, kw_) do {                                        \
    unsigned t0_;                                                       \
    asm("v_pk_max_f16 %0, %1, %2" : "=v"(t0_) : "v"(pw_), "s"(kw_));    \
    asm("v_pk_add_f16 %0, %1, %2" : "=v"(acc_) : "v"(acc_), "v"(t0_));  \
  } while (0)
#define ROW16(s_, q0_, q1_, q2_, q3_)                                       \
    PK2(s_, q0_.x, c0.x); PK2(s_, q0_.y, c0.y); PK2(s_, q0_.z, c0.z); PK2(s_, q0_.w, c0.w); \
    PK2(s_, q1_.x, c1.x); PK2(s_, q1_.y, c1.y); PK2(s_, q1_.z, c1.z); PK2(s_, q1_.w, c1.w); \
    PK2(s_, q2_.x, c2.x); PK2(s_, q2_.y, c2.y); PK2(s_, q2_.z, c2.z); PK2(s_, q2_.w, c2.w); \
    PK2(s_, q3_.x, c3.x); PK2(s_, q3_.y, c3.y); PK2(s_, q3_.z, c3.z); PK2(s_, q3_.w, c3.w);

  float outv0 = 0.f, outv1 = 0.f, outv2 = 0.f, outv3 = 0.f;
  for (int k = 0; k < 64; ++k) {
    // issue next-row prefetch (wrap at 63: harmless re-read of row 0)
    const int kn = (k + 1) & 63;
    const unsigned* kr = kbase + kn * 16;
    u32x4 n0, n1, n2, n3; unsigned nA;
    asm("s_load_dwordx4 %0, %1, 0x0"  : "=s"(n0) : "s"(kr));
    asm("s_load_dwordx4 %0, %1, 0x10" : "=s"(n1) : "s"(kr));
    asm("s_load_dwordx4 %0, %1, 0x20" : "=s"(n2) : "s"(kr));
    asm("s_load_dwordx4 %0, %1, 0x30" : "=s"(n3) : "s"(kr));
    asm("s_load_dword %0, %1, 0x0" : "=s"(nA) : "s"(abase + kn));

    unsigned s0 = 0u, s1 = 0u, s2 = 0u, s3 = 0u;
    ROW16(s0, pa0, pa1, pa2, pa3)
    ROW16(s1, pb0, pb1, pb2, pb3)
    ROW16(s2, pc0, pc1, pc2, pc3)
    ROW16(s3, pd0, pd1, pd2, pd3)

    const float Akf = __builtin_bit_cast(float, cA);
    const f16x2 h0 = bc<f16x2>(s0), h1 = bc<f16x2>(s1);
    const f16x2 h2 = bc<f16x2>(s2), h3 = bc<f16x2>(s3);
    const float S0 = (float)h0[0] + (float)h0[1];
    const float S1 = (float)h1[0] + (float)h1[1];
    const float S2 = (float)h2[0] + (float)h2[1];
    const float S3 = (float)h3[0] + (float)h3[1];
    outv0 += exp2f(fmaf(S0, -2.0f, Ai0 + Akf) * 1.4426950408889634f);
    outv1 += exp2f(fmaf(S1, -2.0f, Ai1 + Akf) * 1.4426950408889634f);
    outv2 += exp2f(fmaf(S2, -2.0f, Ai2 + Akf) * 1.4426950408889634f);
    outv3 += exp2f(fmaf(S3, -2.0f, Ai3 + Akf) * 1.4426950408889634f);

    // retire prefetch, rotate
    asm("s_waitcnt lgkmcnt(0)" : "+s"(n0), "+s"(n1), "+s"(n2), "+s"(n3), "+s"(nA));
    c0 = n0; c1 = n1; c2 = n2; c3 = n3; cA = nA;
  }
#undef ROW16
#undef PK2

  // cross-wave reduction over the 4 k-quarters, then direct store
  outp[w][t] = outv0;
  outp[w][64 + t] = outv1;
  outp[w][128 + t] = outv2;
  outp[w][192 + t] = outv3;
  __syncthreads();
  {
    const int s = tid;  // 256 rows
    float v = outp[0][s] + outp[1][s] + outp[2][s] + outp[3][s];
    out[(size_t)b * 8192 + (size_t)s * 32 + o] = v;
  }
}

extern "C" void kernel_launch(void* const* d_in, const int* in_sizes, int n_in,
                              void* d_out, int out_size, void* d_ws, size_t ws_size,
                              hipStream_t stream) {
  const float* x = (const float*)d_in[0];   // (32,256,1024) f32
  const float* W = (const float*)d_in[1];   // (1024,1024) f32
  float* out = (float*)d_out;               // (32, 8192) f32

  char* ws = (char*)d_ws;
  unsigned short* xb = (unsigned short*)ws;                          // 16 MB
  unsigned short* wbf = (unsigned short*)(ws + (16u << 20));         //  2 MB
  unsigned int* projQ = (unsigned int*)(ws + (18u << 20));           // 16 MB
  float* Abuf = (float*)(ws + (34u << 20));                          //  1 MB

  {
    int n4 = N4X + N4W;  // 2359296
    cast_bf16_kernel<<<(n4 + 255) / 256, 256, 0, stream>>>(x, W, xb, wbf);
  }
  {
    dim3 grid(BS / 128, NO / 128);  // (64, 8)
    gemm_kernel<<<grid, 256, 0, stream>>>(xb, wbf, projQ);
  }
  asum_kernel<<<(32 * BS) / 256, 256, 0, stream>>>(projQ, Abuf);
  dist_kernel<<<32 * 32, 256, 0, stream>>>(projQ, Abuf, out);
}

// Round 12
// 142.652 us; speedup vs baseline: 1.6486x; 1.0156x over previous
//
#include <hip/hip_runtime.h>

// Problem: B=32, S=256, M=1024, N=32, O=32.
// out[b][s*32+o] = sum_k exp(-sum_n |proj[b,s,n,o]-proj[b,k,n,o]|),
// proj[b,s,j] = sum_m x[b,s,m] W[j,m],  j = n*32+o.

#define BS 8192      // B*S rows of x
#define MD 1024      // M
#define NO 1024      // N*O

typedef short short8 __attribute__((ext_vector_type(8)));    // 8 bf16 raw bits
typedef float f32x4 __attribute__((ext_vector_type(4)));
typedef _Float16 f16x2 __attribute__((ext_vector_type(2)));
typedef unsigned u32x4 __attribute__((ext_vector_type(4)));

template <typename T, typename F>
__device__ __forceinline__ T bc(F f) { return __builtin_bit_cast(T, f); }

// v_pk_add_f16, both VGPR
__device__ __forceinline__ unsigned pk_add(unsigned a, unsigned b) {
  unsigned d;
  asm("v_pk_add_f16 %0, %1, %2" : "=v"(d) : "v"(a), "v"(b));
  return d;
}

// force a wave-uniform pointer into SGPRs (readfirstlane both halves)
template <typename T>
__device__ __forceinline__ const T* rfl(const T* p) {
  unsigned long long v = (unsigned long long)p;
  unsigned lo = __builtin_amdgcn_readfirstlane((unsigned)v);
  unsigned hi = __builtin_amdgcn_readfirstlane((unsigned)(v >> 32));
  return (const T*)(((unsigned long long)hi << 32) | (unsigned long long)lo);
}

// ---------------- fused cast f32 -> bf16 (RNE) for x and W ----------------
#define N4X ((BS * MD) / 4)   // 2097152 float4 groups in x
#define N4W ((NO * MD) / 4)   //  262144 in W
__global__ __launch_bounds__(256) void cast_bf16_kernel(const float* __restrict__ x,
                                                        const float* __restrict__ W,
                                                        unsigned short* __restrict__ xb,
                                                        unsigned short* __restrict__ wb) {
  int i = blockIdx.x * 256 + threadIdx.x;
  const float* in;
  unsigned short* out;
  if (i < N4X) { in = x; out = xb; }
  else { i -= N4X; if (i >= N4W) return; in = W; out = wb; }
  float4 v = reinterpret_cast<const float4*>(in)[i];
  ushort4 u;
  unsigned b;
  b = __float_as_uint(v.x); u.x = (unsigned short)((b + 0x7FFFu + ((b >> 16) & 1u)) >> 16);
  b = __float_as_uint(v.y); u.y = (unsigned short)((b + 0x7FFFu + ((b >> 16) & 1u)) >> 16);
  b = __float_as_uint(v.z); u.z = (unsigned short)((b + 0x7FFFu + ((b >> 16) & 1u)) >> 16);
  b = __float_as_uint(v.w); u.w = (unsigned short)((b + 0x7FFFu + ((b >> 16) & 1u)) >> 16);
  reinterpret_cast<ushort4*>(out)[i] = u;
}

// ---------------- GEMM (m97-style): C[j,i] = sum_k W[j,k] x[i,k] ----------------
__global__ __launch_bounds__(256) void gemm_kernel(const unsigned short* __restrict__ xb,
                                                   const unsigned short* __restrict__ wb,
                                                   unsigned int* __restrict__ projQ) {
  const int tid = threadIdx.x;
  const int lane = tid & 63;
  const int w = tid >> 6;
  const int wj = w >> 1, wi = w & 1;           // wave quadrant (64x64)
  const int jt = blockIdx.y * 128;
  const int it = blockIdx.x * 128;
  const int c = lane & 15, h = lane >> 4;

  __shared__ unsigned short Wl[128 * 64];      // 16 KB, row-major [row][64k], swizzled
  __shared__ unsigned short Xl[128 * 64];      // 16 KB

  f32x4 acc[4][4] = {};

  for (int k0 = 0; k0 < MD; k0 += 64) {
#pragma unroll
    for (int rep = 0; rep < 4; rep++) {
      const int p = rep * 256 + w * 64 + lane;
      const int row = p >> 3;
      const int ksg = (p & 7) ^ (row & 7);
      const unsigned short* gw = wb + (size_t)(jt + row) * MD + k0 + ksg * 8;
      const unsigned short* gx = xb + (size_t)(it + row) * MD + k0 + ksg * 8;
      __builtin_amdgcn_global_load_lds(
          (const __attribute__((address_space(1))) void*)gw,
          (__attribute__((address_space(3))) void*)((char*)Wl + rep * 4096 + w * 1024),
          16, 0, 0);
      __builtin_amdgcn_global_load_lds(
          (const __attribute__((address_space(1))) void*)gx,
          (__attribute__((address_space(3))) void*)((char*)Xl + rep * 4096 + w * 1024),
          16, 0, 0);
    }
    __syncthreads();

#pragma unroll
    for (int ks = 0; ks < 2; ks++) {
      short8 af[4], bf[4];
#pragma unroll
      for (int mm = 0; mm < 4; mm++) {
        const int rl = wj * 64 + mm * 16 + c;
        af[mm] = *reinterpret_cast<const short8*>(
            (const char*)Wl + rl * 128 + (((ks * 4 + h) ^ (rl & 7)) * 16));
      }
#pragma unroll
      for (int nn = 0; nn < 4; nn++) {
        const int rl = wi * 64 + nn * 16 + c;
        bf[nn] = *reinterpret_cast<const short8*>(
            (const char*)Xl + rl * 128 + (((ks * 4 + h) ^ (rl & 7)) * 16));
      }
#pragma unroll
      for (int mm = 0; mm < 4; mm++)
#pragma unroll
        for (int nn = 0; nn < 4; nn++)
          acc[mm][nn] = __builtin_amdgcn_mfma_f32_16x16x32_bf16(af[mm], bf[nn], acc[mm][nn], 0, 0, 0);
    }
    __syncthreads();
  }

  const int mbase = (jt + wj * 64) >> 6;
#pragma unroll
  for (int mm01 = 0; mm01 < 2; mm01++) {
#pragma unroll
    for (int r = 0; r < 4; r++) {
      const int o = mm01 * 16 + h * 4 + r;
#pragma unroll
      for (int nn = 0; nn < 4; nn++) {
        const size_t i = (size_t)(it + wi * 64 + nn * 16 + c);
        projQ[(((size_t)o << 13) + i) * 16 + mbase] = bc<unsigned int>(
            __builtin_amdgcn_cvt_pkrtz(acc[mm01][nn][r], acc[mm01 + 2][nn][r]));
      }
    }
  }
}

// ---------------- A[o][i] = f32 row-sum via 4 quarter-chains + merge ----------
// Chain shape MUST bit-match dist's quarter-chains (max(x,x)=x) for exact diag.
__global__ __launch_bounds__(256) void asum_kernel(const unsigned int* __restrict__ projQ,
                                                   float* __restrict__ A) {
  int idx = blockIdx.x * 256 + threadIdx.x;   // 32*8192 total
  int gi = idx & 8191, o = idx >> 13;
  const uint4* p = reinterpret_cast<const uint4*>(projQ + (((size_t)o << 13) + gi) * 16);
  uint4 q0 = p[0], q1 = p[1], q2 = p[2], q3 = p[3];
  unsigned aA, aB, aC, aD;
  aA = pk_add(pk_add(pk_add(q0.x, q0.y), q0.z), q0.w);
  aB = pk_add(pk_add(pk_add(q1.x, q1.y), q1.z), q1.w);
  aC = pk_add(pk_add(pk_add(q2.x, q2.y), q2.z), q2.w);
  aD = pk_add(pk_add(pk_add(q3.x, q3.y), q3.z), q3.w);
  unsigned a = pk_add(pk_add(aA, aB), pk_add(aC, aD));
  f16x2 af = bc<f16x2>(a);
  A[((size_t)o << 13) + gi] = (float)af[0] + (float)af[1];
}

// ---------------- phase 2: 4 rows/lane, quarter-chain ILP, SMEM k-broadcast ------
// Block = (b,o): 4 waves; wave w owns k-quarter [64w,64w+64); lane t owns rows
// {t, t+64, t+128, t+192}. Per row: 4 independent depth-4 chains + 3-merge
// (16 chains in flight across 4 rows -> latency path no longer limits issue).
__global__ __launch_bounds__(256) void dist_kernel(const unsigned int* __restrict__ projQ,
                                                   const float* __restrict__ A,
                                                   float* __restrict__ out) {
  const int tid = threadIdx.x;
  const int t = tid & 63;   // lane
  const int w = tid >> 6;   // wave = k-quarter
  const int bid = blockIdx.x;                   // 32b * 32o
  const int o = bid & 31, b = bid >> 5;
  const size_t obase = ((size_t)o << 13) + b * 256;  // global row-index base

  __shared__ float outp[4][256];     // 4 KB

  // my four rows, per-lane (named uint4s -> nothing to restructure)
  const uint4* PA = reinterpret_cast<const uint4*>(projQ + (obase + t) * 16);
  const uint4 pa0 = PA[0], pa1 = PA[1], pa2 = PA[2], pa3 = PA[3];
  const uint4* PB = reinterpret_cast<const uint4*>(projQ + (obase + 64 + t) * 16);
  const uint4 pb0 = PB[0], pb1 = PB[1], pb2 = PB[2], pb3 = PB[3];
  const uint4* PC = reinterpret_cast<const uint4*>(projQ + (obase + 128 + t) * 16);
  const uint4 pc0 = PC[0], pc1 = PC[1], pc2 = PC[2], pc3 = PC[3];
  const uint4* PD = reinterpret_cast<const uint4*>(projQ + (obase + 192 + t) * 16);
  const uint4 pd0 = PD[0], pd1 = PD[1], pd2 = PD[2], pd3 = PD[3];
  const float Ai0 = A[obase + t];
  const float Ai1 = A[obase + 64 + t];
  const float Ai2 = A[obase + 128 + t];
  const float Ai3 = A[obase + 192 + t];

  // this wave's k-quarter base — wave-uniform, forced into SGPRs
  const unsigned* kbase = rfl(projQ + (obase + w * 64) * 16);
  const float* abase = rfl(A + obase + w * 64);

  // prefetch k-row 0 into SGPRs
  u32x4 c0, c1, c2, c3; unsigned cA;
  asm("s_load_dwordx4 %0, %1, 0x0"  : "=s"(c0) : "s"(kbase));
  asm("s_load_dwordx4 %0, %1, 0x10" : "=s"(c1) : "s"(kbase));
  asm("s_load_dwordx4 %0, %1, 0x20" : "=s"(c2) : "s"(kbase));
  asm("s_load_dwordx4 %0, %1, 0x30" : "=s"(c3) : "s"(kbase));
  asm("s_load_dword %0, %1, 0x0" : "=s"(cA) : "s"(abase));
  asm("s_waitcnt lgkmcnt(0)" : "+s"(c0), "+s"(c1), "+s"(c2), "+s"(c3), "+s"(cA));

#define PKMAX(d_, pw_, kw_) asm("v_pk_max_f16 %0, %1, %2" : "=v"(d_) : "v"(pw_), "s"(kw_))
#define PKADDV(d_, a_, b_)  asm("v_pk_add_f16 %0, %1, %2" : "=v"(d_) : "v"(a_), "v"(b_))
  // depth-4 quarter chain: q_ = ((max0+max1)+max2)+max3   (matches asum quarters)
#define QCH(q_, pv_, cv_) do { unsigned t_;                 \
    PKMAX(q_, pv_.x, cv_.x);                                 \
    PKMAX(t_, pv_.y, cv_.y); PKADDV(q_, q_, t_);             \
    PKMAX(t_, pv_.z, cv_.z); PKADDV(q_, q_, t_);             \
    PKMAX(t_, pv_.w, cv_.w); PKADDV(q_, q_, t_); } while (0)
  // full row: 4 quarter chains + pairwise merge (matches asum merge)
#define ROW16(s_, r0_, r1_, r2_, r3_) do {                   \
    unsigned qa_, qb_, qc_, qd_;                             \
    QCH(qa_, r0_, c0); QCH(qb_, r1_, c1);                    \
    QCH(qc_, r2_, c2); QCH(qd_, r3_, c3);                    \
    PKADDV(qa_, qa_, qb_); PKADDV(qc_, qc_, qd_);            \
    PKADDV(s_, qa_, qc_); } while (0)

  float outv0 = 0.f, outv1 = 0.f, outv2 = 0.f, outv3 = 0.f;
  for (int k = 0; k < 64; ++k) {
    // issue next-row prefetch (wrap at 63: harmless re-read of row 0)
    const int kn = (k + 1) & 63;
    const unsigned* kr = kbase + kn * 16;
    u32x4 n0, n1, n2, n3; unsigned nA;
    asm("s_load_dwordx4 %0, %1, 0x0"  : "=s"(n0) : "s"(kr));
    asm("s_load_dwordx4 %0, %1, 0x10" : "=s"(n1) : "s"(kr));
    asm("s_load_dwordx4 %0, %1, 0x20" : "=s"(n2) : "s"(kr));
    asm("s_load_dwordx4 %0, %1, 0x30" : "=s"(n3) : "s"(kr));
    asm("s_load_dword %0, %1, 0x0" : "=s"(nA) : "s"(abase + kn));

    unsigned s0, s1, s2, s3;
    ROW16(s0, pa0, pa1, pa2, pa3);
    ROW16(s1, pb0, pb1, pb2, pb3);
    ROW16(s2, pc0, pc1, pc2, pc3);
    ROW16(s3, pd0, pd1, pd2, pd3);

    const float Akf = __builtin_bit_cast(float, cA);
    const f16x2 h0 = bc<f16x2>(s0), h1 = bc<f16x2>(s1);
    const f16x2 h2 = bc<f16x2>(s2), h3 = bc<f16x2>(s3);
    const float S0 = (float)h0[0] + (float)h0[1];
    const float S1 = (float)h1[0] + (float)h1[1];
    const float S2 = (float)h2[0] + (float)h2[1];
    const float S3 = (float)h3[0] + (float)h3[1];
    outv0 += exp2f(fmaf(S0, -2.0f, Ai0 + Akf) * 1.4426950408889634f);
    outv1 += exp2f(fmaf(S1, -2.0f, Ai1 + Akf) * 1.4426950408889634f);
    outv2 += exp2f(fmaf(S2, -2.0f, Ai2 + Akf) * 1.4426950408889634f);
    outv3 += exp2f(fmaf(S3, -2.0f, Ai3 + Akf) * 1.4426950408889634f);

    // retire prefetch, rotate
    asm("s_waitcnt lgkmcnt(0)" : "+s"(n0), "+s"(n1), "+s"(n2), "+s"(n3), "+s"(nA));
    c0 = n0; c1 = n1; c2 = n2; c3 = n3; cA = nA;
  }
#undef ROW16
#undef QCH
#undef PKADDV
#undef PKMAX

  // cross-wave reduction over the 4 k-quarters, then direct store
  outp[w][t] = outv0;
  outp[w][64 + t] = outv1;
  outp[w][128 + t] = outv2;
  outp[w][192 + t] = outv3;
  __syncthreads();
  {
    const int s = tid;  // 256 rows
    float v = outp[0][s] + outp[1][s] + outp[2][s] + outp[3][s];
    out[(size_t)b * 8192 + (size_t)s * 32 + o] = v;
  }
}

extern "C" void kernel_launch(void* const* d_in, const int* in_sizes, int n_in,
                              void* d_out, int out_size, void* d_ws, size_t ws_size,
                              hipStream_t stream) {
  const float* x = (const float*)d_in[0];   // (32,256,1024) f32
  const float* W = (const float*)d_in[1];   // (1024,1024) f32
  float* out = (float*)d_out;               // (32, 8192) f32

  char* ws = (char*)d_ws;
  unsigned short* xb = (unsigned short*)ws;                          // 16 MB
  unsigned short* wbf = (unsigned short*)(ws + (16u << 20));         //  2 MB
  unsigned int* projQ = (unsigned int*)(ws + (18u << 20));           // 16 MB
  float* Abuf = (float*)(ws + (34u << 20));                          //  1 MB

  {
    int n4 = N4X + N4W;  // 2359296
    cast_bf16_kernel<<<(n4 + 255) / 256, 256, 0, stream>>>(x, W, xb, wbf);
  }
  {
    dim3 grid(BS / 128, NO / 128);  // (64, 8)
    gemm_kernel<<<grid, 256, 0, stream>>>(xb, wbf, projQ);
  }
  asum_kernel<<<(32 * BS) / 256, 256, 0, stream>>>(projQ, Abuf);
  dist_kernel<<<32 * 32, 256, 0, stream>>>(projQ, Abuf, out);
}